// Round 5
// baseline (208.935 us; speedup 1.0000x reference)
//
#include <hip/hip_runtime.h>

// DPLSafePolicy: logits[16384,13] = x[16384,2048] @ [Wg|Wp|Wa], 3 softmaxes,
// sparse-T unsafe combine, renormalize -> out[16384,5].
//
// R5: K-split-4, ONE row per lane to kill the R4 VGPR spill.
//  k1 pack_weights: fp32 -> fp16, [s][j][512] in d_ws.
//  k2 gemm_partial: grid 4096 (1024 row-tiles x 4 K-chunks), block 256.
//     LDS = 13 KB weight chunk. Lane (hs=l&15, rg=l>>4) owns row
//     rt*16+w*4+rg; all 8 x float4-loads hoisted and issued BEFORE weight
//     staging (latency hidden behind stage+barrier). ~90 VGPR -> ~5 waves/
//     SIMD, launch_bounds(256,3) so no spills. 13 ds_read_b64/iter
//     (128 B span, 4-way broadcast, conflict-free) feed 26 v_dot2_f32_f16.
//     shfl_xor(1,2,4,8) finishes logits; lanes hs<13 write fp32 partials.
//  k3 reduce_epilogue: thread=row, sum 4 partials, biases, softmaxes,
//     combine, write out.

typedef __fp16 h2_t __attribute__((ext_vector_type(2)));
typedef __fp16 h4_t __attribute__((ext_vector_type(4)));

#define WS_PART_OFF 65536   // bytes; fp16 packed weights live at offset 0

__global__ void pack_weights(const float* __restrict__ Wg,
                             const float* __restrict__ Wp,
                             const float* __restrict__ Wa,
                             __fp16* __restrict__ wout)
{
    const int t = blockIdx.x * 256 + threadIdx.x;   // 0..26623 = 13*2048
    const int j = t >> 11, h = t & 2047;
    const int s = h >> 9, hk = h & 511;
    float v;
    if (j < 4)      v = Wg[h * 4 + j];
    else if (j < 8) v = Wp[h * 4 + (j - 4)];
    else            v = Wa[h * 5 + (j - 8)];
    wout[s * 6656 + j * 512 + hk] = (__fp16)v;      // [s][j][hk]
}

__global__ __launch_bounds__(256, 3)
void gemm_partial(const float* __restrict__ x,
                  const __fp16* __restrict__ wpk,
                  float* __restrict__ part)
{
    __shared__ __align__(16) __fp16 wl[13 * 512];   // 13312 B

    const int tid = threadIdx.x;
    const int rt  = blockIdx.x & 1023;  // row tile 0..1023
    const int s   = blockIdx.x >> 10;   // K chunk 0..3

    const int w  = tid >> 6;
    const int l  = tid & 63;
    const int hs = l & 15;
    const int rg = l >> 4;
    const int row = rt * 16 + w * 4 + rg;

    const float4* xg = (const float4*)x;
    const long b0 = (long)row * 512 + s * 128 + hs;   // float4 units

    // issue all 8 x loads first; their latency hides behind weight staging
    float4 xa[8];
    #pragma unroll
    for (int c = 0; c < 8; ++c) xa[c] = xg[b0 + c * 16];

    // stage 13 KB weight chunk: 832 uint4
    {
        const uint4* src = (const uint4*)(wpk + s * 6656);
        uint4* dst = (uint4*)wl;
        int i = tid;
        dst[i] = src[i]; i += 256;
        dst[i] = src[i]; i += 256;
        dst[i] = src[i]; i += 256;
        if (i < 832) dst[i] = src[i];
    }
    __syncthreads();

    float acc[13];
    #pragma unroll
    for (int j = 0; j < 13; ++j) acc[j] = 0.f;

    const h4_t* w4 = (const h4_t*)wl;   // h4 idx = j*128 + c*16 + hs

    #pragma unroll
    for (int c = 0; c < 8; ++c) {
        const h2_t xl = __builtin_amdgcn_cvt_pkrtz(xa[c].x, xa[c].y);
        const h2_t xh = __builtin_amdgcn_cvt_pkrtz(xa[c].z, xa[c].w);
        const int wb = c * 16 + hs;
        #pragma unroll
        for (int j = 0; j < 13; ++j) {
            const h4_t wv = w4[j * 128 + wb];
            const h2_t wlo = __builtin_shufflevector(wv, wv, 0, 1);
            const h2_t whi = __builtin_shufflevector(wv, wv, 2, 3);
#if __has_builtin(__builtin_amdgcn_fdot2)
            acc[j] = __builtin_amdgcn_fdot2(xl, wlo, acc[j], false);
            acc[j] = __builtin_amdgcn_fdot2(xh, whi, acc[j], false);
#else
            acc[j] += (float)xl.x * (float)wlo.x + (float)xl.y * (float)wlo.y
                    + (float)xh.x * (float)whi.x + (float)xh.y * (float)whi.y;
#endif
        }
    }

    #pragma unroll
    for (int j = 0; j < 13; ++j) {
        acc[j] += __shfl_xor(acc[j], 1, 64);
        acc[j] += __shfl_xor(acc[j], 2, 64);
        acc[j] += __shfl_xor(acc[j], 4, 64);
        acc[j] += __shfl_xor(acc[j], 8, 64);
    }

    // lane hs writes column j=hs of its row (cndmask select chain)
    float v = acc[12];
    #pragma unroll
    for (int j = 11; j >= 0; --j) v = (hs == j) ? acc[j] : v;
    if (hs < 13)
        part[((long)(s << 14) + row) * 13 + hs] = v;
}

__global__ __launch_bounds__(256)
void reduce_epilogue(const float* __restrict__ part,
                     const float* __restrict__ bg, const float* __restrict__ bp,
                     const float* __restrict__ ba, float* __restrict__ out)
{
    const int r = blockIdx.x * 256 + threadIdx.x;   // row

    float acc[13];
    #pragma unroll
    for (int j = 0; j < 13; ++j) acc[j] = 0.f;
    #pragma unroll
    for (int s = 0; s < 4; ++s) {
        const long pbase = ((long)(s << 14) + r) * 13;
        #pragma unroll
        for (int j = 0; j < 13; ++j) acc[j] += part[pbase + j];
    }

    const float g0 = acc[0] + bg[0], g1 = acc[1] + bg[1], g2 = acc[2] + bg[2], g3 = acc[3] + bg[3];
    const float q0 = acc[4] + bp[0], q1 = acc[5] + bp[1], q2 = acc[6] + bp[2], q3 = acc[7] + bp[3];
    const float a0 = acc[8] + ba[0], a1 = acc[9] + ba[1], a2 = acc[10] + ba[2],
                a3 = acc[11] + ba[3], a4 = acc[12] + ba[4];

    float m, sum, inv;
    m = fmaxf(fmaxf(g0, g1), fmaxf(g2, g3));
    const float eg0 = __expf(g0 - m), eg1 = __expf(g1 - m), eg2 = __expf(g2 - m), eg3 = __expf(g3 - m);
    sum = eg0 + eg1 + eg2 + eg3; inv = 1.f / sum;
    const float G0 = eg0 * inv, G1 = eg1 * inv, G2 = eg2 * inv, G3 = eg3 * inv;

    m = fmaxf(fmaxf(q0, q1), fmaxf(q2, q3));
    const float ep0 = __expf(q0 - m), ep1 = __expf(q1 - m), ep2 = __expf(q2 - m), ep3 = __expf(q3 - m);
    sum = ep0 + ep1 + ep2 + ep3; inv = 1.f / sum;
    const float P0 = ep0 * inv, P1 = ep1 * inv, P2 = ep2 * inv, P3 = ep3 * inv;

    m = fmaxf(fmaxf(fmaxf(a0, a1), fmaxf(a2, a3)), a4);
    const float ea0 = __expf(a0 - m), ea1 = __expf(a1 - m), ea2 = __expf(a2 - m),
                ea3 = __expf(a3 - m), ea4 = __expf(a4 - m);
    sum = ea0 + ea1 + ea2 + ea3 + ea4; inv = 1.f / sum;
    const float A0 = ea0 * inv, A1 = ea1 * inv, A2 = ea2 * inv, A3 = ea3 * inv, A4 = ea4 * inv;

    const float u0 = P0 * G0 + P1 * G1 + P2 * G2 + P3 * G3;
    const float u1 = P0 * G1 + P2 * G3;
    const float u2 = P1 * G0 + P3 * G2;

    const float j0 = A0 * (1.f - u0), j1 = A1 * (1.f - u1), j2 = A2 * (1.f - u2),
                j3 = A3, j4 = A4;
    const float isd = 1.f / (j0 + j1 + j2 + j3 + j4);

    float* o = out + (long)r * 5;
    o[0] = j0 * isd; o[1] = j1 * isd; o[2] = j2 * isd; o[3] = j3 * isd; o[4] = j4 * isd;
}

extern "C" void kernel_launch(void* const* d_in, const int* in_sizes, int n_in,
                              void* d_out, int out_size, void* d_ws, size_t ws_size,
                              hipStream_t stream) {
    const float* x  = (const float*)d_in[0];
    const float* Wg = (const float*)d_in[1];
    const float* bg = (const float*)d_in[2];
    const float* Wp = (const float*)d_in[3];
    const float* bp = (const float*)d_in[4];
    const float* Wa = (const float*)d_in[5];
    const float* ba = (const float*)d_in[6];
    float* out = (float*)d_out;

    __fp16* wpk = (__fp16*)d_ws;
    float* part = (float*)((char*)d_ws + WS_PART_OFF);

    pack_weights<<<104, 256, 0, stream>>>(Wg, Wp, Wa, wpk);
    gemm_partial<<<4096, 256, 0, stream>>>(x, wpk, part);
    reduce_epilogue<<<64, 256, 0, stream>>>(part, bg, bp, ba, out);
}

// Round 6
// 207.969 us; speedup vs baseline: 1.0046x; 1.0046x over previous
//
#include <hip/hip_runtime.h>

// DPLSafePolicy: logits[16384,13] = x[16384,2048] @ [Wg|Wp|Wa], 3 softmaxes,
// sparse-T unsafe combine, renormalize -> out[16384,5].
//
// R6: MFMA restructure. mfma_f32_16x16x32_f16: wave = 16 rows x 16 cols
// (13 used) per K-step of 32. ~130 instr per wave-K-half vs ~3500 for the
// R5 fdot2 structure.
//  k1 pack_bfrag: B-operand fragment table [iter64][lane64] x 8 fp16
//     (B[k=(l>>4)*8+j][n=l&15], n>=13 zero) -> 64 KB in d_ws.
//  k2 gemm_mfma: grid 512, block 256 = 4 waves = 2 row-tiles x 2 K-halves.
//     No weight LDS, no staging barrier: B-frags from L2-hot global
//     (512*4 waves*32 KB = 64 MB @ L2 BW ~ 2 us). A-frags direct from x
//     (lane m=l&15 row, kg=l>>4: 2x dwordx4 per iter; per-row 128 B lines,
//     L1 absorbs the kg interleave). 4-deep register prefetch = 12 loads
//     in flight/lane. D-frag (col=l&15, row=(l>>4)*4+reg) -> LDS transpose
//     (8.7 KB, 2-way bank alias = free), sum K-halves, epilogue inline.
//     No partials workspace, no reduce kernel.

typedef __fp16 h2_t __attribute__((ext_vector_type(2)));
typedef __fp16 h4_t __attribute__((ext_vector_type(4)));
typedef __fp16 h8_t __attribute__((ext_vector_type(8)));
typedef float f32x4 __attribute__((ext_vector_type(4)));

__global__ void pack_bfrag(const float* __restrict__ Wg,
                           const float* __restrict__ Wp,
                           const float* __restrict__ Wa,
                           h8_t* __restrict__ bfrag)
{
    const int t = blockIdx.x * 256 + threadIdx.x;   // 0..4095
    const int iter = t >> 6, lane = t & 63;
    const int n = lane & 15, kg = lane >> 4;
    h8_t v;
    #pragma unroll
    for (int j = 0; j < 8; ++j) {
        const int k = iter * 32 + kg * 8 + j;
        float f;
        if (n < 4)       f = Wg[k * 4 + n];
        else if (n < 8)  f = Wp[k * 4 + (n - 4)];
        else if (n < 13) f = Wa[k * 5 + (n - 8)];
        else             f = 0.f;
        v[j] = (__fp16)f;
    }
    bfrag[t] = v;
}

__global__ __launch_bounds__(256, 2)
void gemm_mfma(const float* __restrict__ x,
               const h8_t* __restrict__ bfrag,
               const float* __restrict__ bg, const float* __restrict__ bp,
               const float* __restrict__ ba, float* __restrict__ out)
{
    __shared__ float dt[2][2][16][17];   // [rt2][ks][row][col], 8704 B

    const int tid = threadIdx.x;
    const int w   = tid >> 6;       // wave 0..3
    const int l   = tid & 63;
    const int rt2 = w & 1;          // row-tile within block
    const int ks  = w >> 1;         // K half
    const int row0 = blockIdx.x * 32 + rt2 * 16;
    const int m  = l & 15;          // A row / D col
    const int kg = l >> 4;          // k-group

    const float4* xg = (const float4*)x;
    const long base = (long)(row0 + m) * 512 + ks * 256 + kg * 2;  // float4 units
    const h8_t* bf = bfrag + (ks * 32) * 64 + l;

    // 4-deep prefetch: 8 x-loads + 4 b-loads in flight per lane
    float4 pa[4], pb[4];
    h8_t   pf[4];
    #pragma unroll
    for (int d = 0; d < 4; ++d) {
        pa[d] = xg[base + d * 8];
        pb[d] = xg[base + d * 8 + 1];
        pf[d] = bf[d * 64];
    }

    f32x4 acc = {0.f, 0.f, 0.f, 0.f};

    #pragma unroll 4
    for (int i = 0; i < 32; ++i) {
        const int s = i & 3;
        const float4 xa = pa[s], xb = pb[s];
        const h8_t b8 = pf[s];
        if (i + 4 < 32) {
            pa[s] = xg[base + (i + 4) * 8];
            pb[s] = xg[base + (i + 4) * 8 + 1];
            pf[s] = bf[(i + 4) * 64];
        }
        const h2_t a01 = __builtin_amdgcn_cvt_pkrtz(xa.x, xa.y);
        const h2_t a23 = __builtin_amdgcn_cvt_pkrtz(xa.z, xa.w);
        const h2_t a45 = __builtin_amdgcn_cvt_pkrtz(xb.x, xb.y);
        const h2_t a67 = __builtin_amdgcn_cvt_pkrtz(xb.z, xb.w);
        const h4_t alo = __builtin_shufflevector(a01, a23, 0, 1, 2, 3);
        const h4_t ahi = __builtin_shufflevector(a45, a67, 0, 1, 2, 3);
        const h8_t a8  = __builtin_shufflevector(alo, ahi, 0, 1, 2, 3, 4, 5, 6, 7);
        acc = __builtin_amdgcn_mfma_f32_16x16x32_f16(a8, b8, acc, 0, 0, 0);
    }

    // D-frag: lane l, reg r -> D[row=kg*4+r][col=m]
    #pragma unroll
    for (int r = 0; r < 4; ++r)
        dt[rt2][ks][kg * 4 + r][m] = acc[r];
    __syncthreads();

    // epilogue: waves 0,1 (=row-tile), lanes 0..15 (=row within tile)
    if (w < 2 && l < 16) {
        float lg[13];
        #pragma unroll
        for (int c = 0; c < 13; ++c)
            lg[c] = dt[w][0][l][c] + dt[w][1][l][c];

        const float g0 = lg[0] + bg[0], g1 = lg[1] + bg[1], g2 = lg[2] + bg[2], g3 = lg[3] + bg[3];
        const float q0 = lg[4] + bp[0], q1 = lg[5] + bp[1], q2 = lg[6] + bp[2], q3 = lg[7] + bp[3];
        const float a0 = lg[8] + ba[0], a1 = lg[9] + ba[1], a2 = lg[10] + ba[2],
                    a3 = lg[11] + ba[3], a4 = lg[12] + ba[4];

        float mx, sum, inv;
        mx = fmaxf(fmaxf(g0, g1), fmaxf(g2, g3));
        const float eg0 = __expf(g0 - mx), eg1 = __expf(g1 - mx), eg2 = __expf(g2 - mx), eg3 = __expf(g3 - mx);
        sum = eg0 + eg1 + eg2 + eg3; inv = 1.f / sum;
        const float G0 = eg0 * inv, G1 = eg1 * inv, G2 = eg2 * inv, G3 = eg3 * inv;

        mx = fmaxf(fmaxf(q0, q1), fmaxf(q2, q3));
        const float ep0 = __expf(q0 - mx), ep1 = __expf(q1 - mx), ep2 = __expf(q2 - mx), ep3 = __expf(q3 - mx);
        sum = ep0 + ep1 + ep2 + ep3; inv = 1.f / sum;
        const float P0 = ep0 * inv, P1 = ep1 * inv, P2 = ep2 * inv, P3 = ep3 * inv;

        mx = fmaxf(fmaxf(fmaxf(a0, a1), fmaxf(a2, a3)), a4);
        const float ea0 = __expf(a0 - mx), ea1 = __expf(a1 - mx), ea2 = __expf(a2 - mx),
                    ea3 = __expf(a3 - mx), ea4 = __expf(a4 - mx);
        sum = ea0 + ea1 + ea2 + ea3 + ea4; inv = 1.f / sum;
        const float A0 = ea0 * inv, A1 = ea1 * inv, A2 = ea2 * inv, A3 = ea3 * inv, A4 = ea4 * inv;

        const float u0 = P0 * G0 + P1 * G1 + P2 * G2 + P3 * G3;  // stay
        const float u1 = P0 * G1 + P2 * G3;                      // up
        const float u2 = P1 * G0 + P3 * G2;                      // down

        const float j0 = A0 * (1.f - u0), j1 = A1 * (1.f - u1), j2 = A2 * (1.f - u2),
                    j3 = A3, j4 = A4;
        const float isd = 1.f / (j0 + j1 + j2 + j3 + j4);

        float* o = out + (long)(row0 + l) * 5;
        o[0] = j0 * isd; o[1] = j1 * isd; o[2] = j2 * isd; o[3] = j3 * isd; o[4] = j4 * isd;
    }
}

extern "C" void kernel_launch(void* const* d_in, const int* in_sizes, int n_in,
                              void* d_out, int out_size, void* d_ws, size_t ws_size,
                              hipStream_t stream) {
    const float* x  = (const float*)d_in[0];
    const float* Wg = (const float*)d_in[1];
    const float* bg = (const float*)d_in[2];
    const float* Wp = (const float*)d_in[3];
    const float* bp = (const float*)d_in[4];
    const float* Wa = (const float*)d_in[5];
    const float* ba = (const float*)d_in[6];
    float* out = (float*)d_out;

    h8_t* bfrag = (h8_t*)d_ws;   // 64 KB fragment table

    pack_bfrag<<<16, 256, 0, stream>>>(Wg, Wp, Wa, bfrag);
    gemm_mfma<<<512, 256, 0, stream>>>(x, bfrag, bg, bp, ba, out);
}

// Round 7
// 204.377 us; speedup vs baseline: 1.0223x; 1.0176x over previous
//
#include <hip/hip_runtime.h>

// DPLSafePolicy: logits[16384,13] = x[16384,2048] @ [Wg|Wp|Wa], 3 softmaxes,
// sparse-T unsafe combine, renormalize -> out[16384,5].
//
// R7 = R6 (MFMA, 2 kernels) + K-phase staggering to kill HBM partition
// camping: every prior round swept K in lockstep, so at inner-iter i the
// whole GPU read a ~128B column of the address space mod 8KB (rows are
// 8KB-aligned) -> channel serialization at ~2.2 TB/s. Each wave now
// rotates its K order by phase=(blockIdx*4+w)&31, spreading instantaneous
// accesses over the full row period. fp32 accumulate reorder is benign.
//  k1 pack_bfrag: B fragment table [iter64][lane64] x 8 fp16 -> 64 KB d_ws.
//  k2 gemm_mfma: grid 512, block 256 = 4 waves = 2 row-tiles x 2 K-halves;
//     B-frags from L2-hot global; A direct from x with 4-deep rotated
//     prefetch; D-frag -> LDS transpose; K-halves summed; epilogue inline.

typedef __fp16 h2_t __attribute__((ext_vector_type(2)));
typedef __fp16 h4_t __attribute__((ext_vector_type(4)));
typedef __fp16 h8_t __attribute__((ext_vector_type(8)));
typedef float f32x4 __attribute__((ext_vector_type(4)));

__global__ void pack_bfrag(const float* __restrict__ Wg,
                           const float* __restrict__ Wp,
                           const float* __restrict__ Wa,
                           h8_t* __restrict__ bfrag)
{
    const int t = blockIdx.x * 256 + threadIdx.x;   // 0..4095
    const int iter = t >> 6, lane = t & 63;
    const int n = lane & 15, kg = lane >> 4;
    h8_t v;
    #pragma unroll
    for (int j = 0; j < 8; ++j) {
        const int k = iter * 32 + kg * 8 + j;
        float f;
        if (n < 4)       f = Wg[k * 4 + n];
        else if (n < 8)  f = Wp[k * 4 + (n - 4)];
        else if (n < 13) f = Wa[k * 5 + (n - 8)];
        else             f = 0.f;
        v[j] = (__fp16)f;
    }
    bfrag[t] = v;
}

__global__ __launch_bounds__(256, 2)
void gemm_mfma(const float* __restrict__ x,
               const h8_t* __restrict__ bfrag,
               const float* __restrict__ bg, const float* __restrict__ bp,
               const float* __restrict__ ba, float* __restrict__ out)
{
    __shared__ float dt[2][2][16][17];   // [rt2][ks][row][col], 8704 B

    const int tid = threadIdx.x;
    const int w   = tid >> 6;       // wave 0..3
    const int l   = tid & 63;
    const int rt2 = w & 1;          // row-tile within block
    const int ks  = w >> 1;         // K half
    const int row0 = blockIdx.x * 32 + rt2 * 16;
    const int m  = l & 15;          // A row / D col
    const int kg = l >> 4;          // k-group

    // per-wave K-phase: spreads the machine's instantaneous address column
    const int phase = (blockIdx.x * 4 + w) & 31;

    const float4* xg = (const float4*)x;
    const long base = (long)(row0 + m) * 512 + ks * 256 + kg * 2;  // float4 units
    const h8_t* bf = bfrag + (ks * 32) * 64 + l;

    // 4-deep rotated prefetch: 12 loads in flight per lane
    float4 pa[4], pb[4];
    h8_t   pf[4];
    #pragma unroll
    for (int d = 0; d < 4; ++d) {
        const int idx = (phase + d) & 31;
        pa[d] = xg[base + idx * 8];
        pb[d] = xg[base + idx * 8 + 1];
        pf[d] = bf[idx * 64];
    }

    f32x4 acc = {0.f, 0.f, 0.f, 0.f};

    #pragma unroll 4
    for (int i = 0; i < 32; ++i) {
        const int s = i & 3;
        const float4 xa = pa[s], xb = pb[s];
        const h8_t b8 = pf[s];
        if (i + 4 < 32) {
            const int idx = (phase + i + 4) & 31;
            pa[s] = xg[base + idx * 8];
            pb[s] = xg[base + idx * 8 + 1];
            pf[s] = bf[idx * 64];
        }
        const h2_t a01 = __builtin_amdgcn_cvt_pkrtz(xa.x, xa.y);
        const h2_t a23 = __builtin_amdgcn_cvt_pkrtz(xa.z, xa.w);
        const h2_t a45 = __builtin_amdgcn_cvt_pkrtz(xb.x, xb.y);
        const h2_t a67 = __builtin_amdgcn_cvt_pkrtz(xb.z, xb.w);
        const h4_t alo = __builtin_shufflevector(a01, a23, 0, 1, 2, 3);
        const h4_t ahi = __builtin_shufflevector(a45, a67, 0, 1, 2, 3);
        const h8_t a8  = __builtin_shufflevector(alo, ahi, 0, 1, 2, 3, 4, 5, 6, 7);
        acc = __builtin_amdgcn_mfma_f32_16x16x32_f16(a8, b8, acc, 0, 0, 0);
    }

    // D-frag: lane l, reg r -> D[row=kg*4+r][col=m]
    #pragma unroll
    for (int r = 0; r < 4; ++r)
        dt[rt2][ks][kg * 4 + r][m] = acc[r];
    __syncthreads();

    // epilogue: waves 0,1 (=row-tile), lanes 0..15 (=row within tile)
    if (w < 2 && l < 16) {
        float lg[13];
        #pragma unroll
        for (int c = 0; c < 13; ++c)
            lg[c] = dt[w][0][l][c] + dt[w][1][l][c];

        const float g0 = lg[0] + bg[0], g1 = lg[1] + bg[1], g2 = lg[2] + bg[2], g3 = lg[3] + bg[3];
        const float q0 = lg[4] + bp[0], q1 = lg[5] + bp[1], q2 = lg[6] + bp[2], q3 = lg[7] + bp[3];
        const float a0 = lg[8] + ba[0], a1 = lg[9] + ba[1], a2 = lg[10] + ba[2],
                    a3 = lg[11] + ba[3], a4 = lg[12] + ba[4];

        float mx, sum, inv;
        mx = fmaxf(fmaxf(g0, g1), fmaxf(g2, g3));
        const float eg0 = __expf(g0 - mx), eg1 = __expf(g1 - mx), eg2 = __expf(g2 - mx), eg3 = __expf(g3 - mx);
        sum = eg0 + eg1 + eg2 + eg3; inv = 1.f / sum;
        const float G0 = eg0 * inv, G1 = eg1 * inv, G2 = eg2 * inv, G3 = eg3 * inv;

        mx = fmaxf(fmaxf(q0, q1), fmaxf(q2, q3));
        const float ep0 = __expf(q0 - mx), ep1 = __expf(q1 - mx), ep2 = __expf(q2 - mx), ep3 = __expf(q3 - mx);
        sum = ep0 + ep1 + ep2 + ep3; inv = 1.f / sum;
        const float P0 = ep0 * inv, P1 = ep1 * inv, P2 = ep2 * inv, P3 = ep3 * inv;

        mx = fmaxf(fmaxf(fmaxf(a0, a1), fmaxf(a2, a3)), a4);
        const float ea0 = __expf(a0 - mx), ea1 = __expf(a1 - mx), ea2 = __expf(a2 - mx),
                    ea3 = __expf(a3 - mx), ea4 = __expf(a4 - mx);
        sum = ea0 + ea1 + ea2 + ea3 + ea4; inv = 1.f / sum;
        const float A0 = ea0 * inv, A1 = ea1 * inv, A2 = ea2 * inv, A3 = ea3 * inv, A4 = ea4 * inv;

        const float u0 = P0 * G0 + P1 * G1 + P2 * G2 + P3 * G3;  // stay
        const float u1 = P0 * G1 + P2 * G3;                      // up
        const float u2 = P1 * G0 + P3 * G2;                      // down

        const float j0 = A0 * (1.f - u0), j1 = A1 * (1.f - u1), j2 = A2 * (1.f - u2),
                    j3 = A3, j4 = A4;
        const float isd = 1.f / (j0 + j1 + j2 + j3 + j4);

        float* o = out + (long)(row0 + l) * 5;
        o[0] = j0 * isd; o[1] = j1 * isd; o[2] = j2 * isd; o[3] = j3 * isd; o[4] = j4 * isd;
    }
}

extern "C" void kernel_launch(void* const* d_in, const int* in_sizes, int n_in,
                              void* d_out, int out_size, void* d_ws, size_t ws_size,
                              hipStream_t stream) {
    const float* x  = (const float*)d_in[0];
    const float* Wg = (const float*)d_in[1];
    const float* bg = (const float*)d_in[2];
    const float* Wp = (const float*)d_in[3];
    const float* bp = (const float*)d_in[4];
    const float* Wa = (const float*)d_in[5];
    const float* ba = (const float*)d_in[6];
    float* out = (float*)d_out;

    h8_t* bfrag = (h8_t*)d_ws;   // 64 KB fragment table

    pack_bfrag<<<16, 256, 0, stream>>>(Wg, Wp, Wa, bfrag);
    gemm_mfma<<<512, 256, 0, stream>>>(x, bfrag, bg, bp, ba, out);
}